// Round 19
// baseline (1035.897 us; speedup 1.0000x reference)
//
#include <hip/hip_runtime.h>
#include <math.h>
#include <stdint.h>

// x: [65536 x 256] f32, codebook: [4096 x 256] f32
// d_out (f32): ids(65536 as float) | emb(65536*256) | loss(1)

#define TOKENS 65536
#define DIM 256
#define KCB 4096

#define TB 256                 // tokens per block; 8 waves = 4 token-quarters x 2 code-halves
#define DELTA_SCALE 0.03125f   // 2^-5 * ||x|| band (sound: >= 4x bf16 dot error bound)
#define LIST_CAP (1u << 21)    // candidate list capacity
#define SCAP 8192              // per-block LDS candidate cap (expected ~2K)
#define PRIME 16               // primed cts (no extraction; recomputed at end w/ final thr)
#define RBLOCKS 2048           // rescore grid (XCD-contiguous chunk assignment)

typedef short bf16x8 __attribute__((ext_vector_type(8)));
typedef float f32x4 __attribute__((ext_vector_type(4)));

__device__ inline short f2bf(float f) {  // RNE float->bf16
    uint32_t u = __float_as_uint(f);
    u += 0x7FFF + ((u >> 16) & 1);
    return (short)(u >> 16);
}

// validated fp32 candidate scoring: sequential-k float4 fmaf chain + u64 (dist,id)
// atomicMin — byte-identical arithmetic/semantics to the R11-R17 rescore path.
__device__ inline void rescore_one(const float* __restrict__ x, const float* __restrict__ cbn,
                                   const float* __restrict__ invnx,
                                   unsigned long long* __restrict__ win,
                                   uint32_t t, uint32_t c) {
    const float4* xp = (const float4*)(x + (size_t)t * DIM);
    const float4* cp = (const float4*)(cbn + (size_t)c * DIM);
    float acc = 0.0f;
#pragma unroll 8
    for (int k = 0; k < DIM / 4; ++k) {
        float4 xv = xp[k];
        float4 cv = cp[k];
        acc = fmaf(xv.x, cv.x, acc);
        acc = fmaf(xv.y, cv.y, acc);
        acc = fmaf(xv.z, cv.z, acc);
        acc = fmaf(xv.w, cv.w, acc);
    }
    float s = acc * invnx[t];
    float dist = 1.0f - s;
    uint32_t u = __float_as_uint(dist);
    u = (u & 0x80000000u) ? ~u : (u | 0x80000000u);  // order-preserving map
    unsigned long long key = ((unsigned long long)u << 32) | c;
    atomicMin(win + t, key);
}

// ---------------- kernel 1: fused prep (byte-identical to R16-R18 validated) ----------------
__global__ void prep_all(const float* __restrict__ cb, const float* __restrict__ x,
                         float* __restrict__ cbn, short* __restrict__ cbh2,
                         float* __restrict__ xnorm, float* __restrict__ invnx) {
    int bid  = blockIdx.x;
    int w    = threadIdx.x >> 6;
    int lane = threadIdx.x & 63;
    if (bid < KCB / 4) {
        int row = bid * 4 + w;                        // code c
        float4 v = *(const float4*)(cb + (size_t)row * DIM + lane * 4);
        float ss = v.x * v.x + v.y * v.y + v.z * v.z + v.w * v.w;
#pragma unroll
        for (int off = 32; off; off >>= 1) ss += __shfl_xor(ss, off);
        float scale = 1.0f / fmaxf(sqrtf(ss), 1e-12f);
        float4 o = {v.x * scale, v.y * scale, v.z * scale, v.w * scale};
        *(float4*)(cbn + (size_t)row * DIM + lane * 4) = o;
        short4 h = {f2bf(o.x), f2bf(o.y), f2bf(o.z), f2bf(o.w)};
        int g = row >> 4, l15 = row & 15;
        int kst = lane >> 3, q = (lane >> 1) & 3, jhalf = lane & 1;
        size_t dst = ((size_t)((g * 8 + kst) * 64 + q * 16 + l15)) * 8 + jhalf * 4;
        *(short4*)(cbh2 + dst) = h;
    } else {
        int row = (bid - KCB / 4) * 4 + w;            // token t
        float4 v = *(const float4*)(x + (size_t)row * DIM + lane * 4);
        float ss = v.x * v.x + v.y * v.y + v.z * v.z + v.w * v.w;
#pragma unroll
        for (int off = 32; off; off >>= 1) ss += __shfl_xor(ss, off);
        if (lane == 0) {
            float n = fmaxf(sqrtf(ss), 1e-12f);
            xnorm[row] = n;
            invnx[row] = 1.0f / n;
        }
    }
}

// load 8 B-frags for ct index (cti) into buf
#define LOADB(buf, cti)                                                            \
    {                                                                              \
        const short* bp_ = cbh2 + (size_t)(ch * 128 + (cti)) * 4096 + lane * 8;    \
        _Pragma("unroll")                                                          \
        for (int j = 0; j < 8; ++j) buf[j] = *(const bf16x8*)(bp_ + j * 512);      \
    }

// fresh-zero acc, kst-ascending MFMA (bit-identical per-acc chain to R8-R18)
#define COMPUTE(buf)                                                               \
    {                                                                              \
        _Pragma("unroll")                                                          \
        for (int mf = 0; mf < 4; ++mf) acc[mf] = (f32x4){0.f, 0.f, 0.f, 0.f};      \
        _Pragma("unroll")                                                          \
        for (int kst = 0; kst < 8; ++kst)                                          \
            _Pragma("unroll")                                                      \
            for (int mf = 0; mf < 4; ++mf)                                         \
                acc[mf] = __builtin_amdgcn_mfma_f32_16x16x32_bf16(                 \
                    areg[mf][kst], buf[kst], acc[mf], 0, 0, 0);                    \
    }

#define FOLDMAX()                                                                  \
    {                                                                              \
        _Pragma("unroll")                                                          \
        for (int mf = 0; mf < 4; ++mf)                                             \
            _Pragma("unroll")                                                      \
            for (int r = 0; r < 4; ++r)                                            \
                rmax[mf][r] = fmaxf(rmax[mf][r], acc[mf][r]);                      \
    }

// refresh live threshold from cross-lane running max (always <= final threshold)
#define REFRESH()                                                                  \
    {                                                                              \
        _Pragma("unroll")                                                          \
        for (int mf = 0; mf < 4; ++mf)                                             \
            _Pragma("unroll")                                                      \
            for (int r = 0; r < 4; ++r) {                                          \
                float v = rmax[mf][r];                                             \
                _Pragma("unroll")                                                  \
                for (int o = 1; o < 16; o <<= 1) v = fmaxf(v, __shfl_xor(v, o));   \
                thrv[mf][r] = v - xnd[mf][r];                                      \
            }                                                                      \
    }

// extraction vs threshold array THR; LDS overflow -> inline fp32 rescore (no list/cnt)
#define EXTRACT_V(cti, THR)                                                        \
    {                                                                              \
        _Pragma("unroll")                                                          \
        for (int mf = 0; mf < 4; ++mf)                                             \
            _Pragma("unroll")                                                      \
            for (int r = 0; r < 4; ++r) {                                          \
                if (acc[mf][r] >= THR[mf][r]) {                                    \
                    uint32_t t = twb + mf * 16 + q * 4 + r;                        \
                    uint32_t c = ch * 2048 + (cti) * 16 + l15;                     \
                    uint32_t idx = atomicAdd(&s_cnt, 1u);                          \
                    if (idx < SCAP) s_list[idx] = (t << 12) | c;                   \
                    else rescore_one(x, cbn, invnx, win, t, c);                    \
                }                                                                  \
            }                                                                      \
    }

// ---------------- kernel 2: SINGLE-SWEEP MFMA select, pipelined B ----------------
// Block = 256 tokens, 8 waves: token quarter tq = wid>>1 (64 tokens, areg-resident),
// code half ch = wid&1 (2048 codes, 128 ct of 16). ONE sweep with running threshold
// (refresh cadence 16 = the R13-validated value; thrv <= thr_final always -> extracted
// set is a superset of the exact band; fp32 rescore resolves winners). Primed cts
// [0,PRIME) recomputed vs the exact final threshold (bit-identical reduce chain to
// R10-R18). Overflow path inline-rescoras (validated chain); batched copy-out is the
// ONLY cnt writer. B double-buffer + sched_barrier pipeline from validated R17.
__global__ __launch_bounds__(512, 2) void mfma_select(
    const float* __restrict__ x, const short* __restrict__ cbh2,
    const float* __restrict__ xnorm, const float* __restrict__ cbn,
    const float* __restrict__ invnx,
    uint32_t* __restrict__ list, uint32_t* __restrict__ cnt,
    unsigned long long* __restrict__ win) {
    __shared__ uint32_t s_list[SCAP];
    __shared__ uint32_t s_cnt, s_base;
    __shared__ float maxbuf[2][TB];

    const int tid  = threadIdx.x;
    const int lane = tid & 63;
    const int wid  = tid >> 6;
    const int tq   = wid >> 1;          // token quarter (0..3)
    const int ch   = wid & 1;           // code half (0..1)
    const int l15  = lane & 15, q = lane >> 4;
    const int tb   = blockIdx.x * TB;
    const int twb  = tb + tq * 64;      // this wave's 64-token base

    if (tid == 0) s_cnt = 0;

    // ---- load A into registers: 4 mf x 8 kst fragments (tokens twb + mf*16 + l15) ----
    bf16x8 areg[4][8];
#pragma unroll
    for (int mf = 0; mf < 4; ++mf) {
        const float* xr = x + (size_t)(twb + mf * 16 + l15) * DIM + q * 8;
#pragma unroll
        for (int kst = 0; kst < 8; ++kst) {
            float4 f0 = *(const float4*)(xr + kst * 32);
            float4 f1 = *(const float4*)(xr + kst * 32 + 4);
            bf16x8 h;
            h[0] = f2bf(f0.x); h[1] = f2bf(f0.y); h[2] = f2bf(f0.z); h[3] = f2bf(f0.w);
            h[4] = f2bf(f1.x); h[5] = f2bf(f1.y); h[6] = f2bf(f1.z); h[7] = f2bf(f1.w);
            areg[mf][kst] = h;
        }
    }

    // per-lane delta = DELTA_SCALE * ||x|| for this lane's 16 token rows
    float xnd[4][4];
#pragma unroll
    for (int mf = 0; mf < 4; ++mf)
#pragma unroll
        for (int r = 0; r < 4; ++r)
            xnd[mf][r] = DELTA_SCALE * xnorm[twb + mf * 16 + q * 4 + r];

    __syncthreads();   // s_cnt init visible before any extraction atomics

    float rmax[4][4], thrv[4][4];
#pragma unroll
    for (int mf = 0; mf < 4; ++mf)
#pragma unroll
        for (int r = 0; r < 4; ++r) { rmax[mf][r] = -3.0e38f; thrv[mf][r] = 3.0e38f; }

    // ---- single pipelined sweep over this wave's 2048 codes (16/ct) ----
    {
        bf16x8 bA[8], bB[8];
        f32x4 acc[4];
        LOADB(bA, 0)
        for (int ct = 0; ct < 128; ct += 2) {
            if ((ct & 15) == 0 && ct) REFRESH()
            LOADB(bB, ct + 1)
            __builtin_amdgcn_sched_barrier(0);
            COMPUTE(bA)
            if (ct >= PRIME) EXTRACT_V(ct, thrv)
            FOLDMAX()
            int ctn = (ct + 2 < 128) ? ct + 2 : 127;  // clamped dummy on last iter
            LOADB(bA, ctn)
            __builtin_amdgcn_sched_barrier(0);
            COMPUTE(bB)
            if (ct + 1 >= PRIME) EXTRACT_V(ct + 1, thrv)
            FOLDMAX()
        }
    }

    // ---- exact final threshold (bit-identical chain to R10-R18) ----
#pragma unroll
    for (int mf = 0; mf < 4; ++mf)
#pragma unroll
        for (int r = 0; r < 4; ++r) {
            float v = rmax[mf][r];
#pragma unroll
            for (int o = 1; o < 16; o <<= 1) v = fmaxf(v, __shfl_xor(v, o));
            rmax[mf][r] = v;
        }
    if (l15 == 0) {
#pragma unroll
        for (int mf = 0; mf < 4; ++mf)
#pragma unroll
            for (int r = 0; r < 4; ++r)
                maxbuf[ch][tq * 64 + mf * 16 + q * 4 + r] = rmax[mf][r];
    }
    __syncthreads();
    float thr[4][4];
#pragma unroll
    for (int mf = 0; mf < 4; ++mf)
#pragma unroll
        for (int r = 0; r < 4; ++r) {
            int tl = tq * 64 + mf * 16 + q * 4 + r;
            thr[mf][r] = fmaxf(maxbuf[0][tl], maxbuf[1][tl]) - xnd[mf][r];
        }

    // ---- recompute primed cts [0,PRIME) with the exact final threshold ----
    {
        bf16x8 bA[8];
        f32x4 acc[4];
        for (int ct = 0; ct < PRIME; ++ct) {
            LOADB(bA, ct)
            __builtin_amdgcn_sched_barrier(0);
            COMPUTE(bA)
            EXTRACT_V(ct, thr)
        }
    }

    // ---- batched copy-out: one global atomic per block (the ONLY cnt writer) ----
    __syncthreads();
    if (tid == 0) {
        uint32_t m = s_cnt;
        if (m > SCAP) m = SCAP;
        s_base = atomicAdd(cnt, m);
        s_cnt = m;
    }
    __syncthreads();
    for (uint32_t i = tid; i < s_cnt; i += 512) {
        uint32_t idx = s_base + i;
        if (idx < LIST_CAP) list[idx] = s_list[i];
    }
}

// ---------------- kernel 3: fp32 rescore, XCD-contiguous chunks (R16/R17-validated) --------
__global__ void rescore(const float* __restrict__ x, const float* __restrict__ cbn,
                        const float* __restrict__ invnx,
                        const uint32_t* __restrict__ list, const uint32_t* __restrict__ cnt,
                        unsigned long long* __restrict__ win) {
    uint32_t n = *cnt;
    if (n > LIST_CAP) n = LIST_CAP;
    uint32_t swz = (blockIdx.x & 7) * (RBLOCKS / 8) + (blockIdx.x >> 3);
    uint32_t per = (n + RBLOCKS - 1) / RBLOCKS;
    uint32_t lo  = swz * per;
    uint32_t hi  = lo + per;
    if (hi > n) hi = n;
    for (uint32_t e = lo + threadIdx.x; e < hi; e += blockDim.x) {
        uint32_t v = list[e];
        rescore_one(x, cbn, invnx, win, v >> 12, v & 4095);
    }
}

// ---------------- kernel 4: gather + weighted emb + per-block loss partial ----------------
__global__ void epilogue_kernel(const float* __restrict__ x, const float* __restrict__ cbn,
                                const float* __restrict__ invnx,
                                const unsigned long long* __restrict__ win,
                                float* __restrict__ ids_f,
                                float* __restrict__ emb, float* __restrict__ partials) {
    int w    = threadIdx.x >> 6;
    int lane = threadIdx.x & 63;
    int t    = blockIdx.x * 4 + w;
    int id   = (int)(win[t] & 0xFFFFFFFFull);
    if ((unsigned)id > 4095u) id = 0;  // safety: never expected to trigger
    if (lane == 0) ids_f[t] = (float)id;

    float4 c4 = *(const float4*)(cbn + (size_t)id * DIM + lane * 4);
    float4 x4 = *(const float4*)(x + (size_t)t * DIM + lane * 4);
    float dxc = c4.x * x4.x + c4.y * x4.y + c4.z * x4.z + c4.w * x4.w;
    float ssc = c4.x * c4.x + c4.y * c4.y + c4.z * c4.z + c4.w * c4.w;
#pragma unroll
    for (int off = 32; off; off >>= 1) {
        dxc += __shfl_xor(dxc, off);
        ssc += __shfl_xor(ssc, off);
    }
    float cosk = fmaxf(dxc, 1e-6f);
    float4 o = {cosk * c4.x, cosk * c4.y, cosk * c4.z, cosk * c4.w};
    *(float4*)(emb + (size_t)t * DIM + lane * 4) = o;

    float invnc = 1.0f / fmaxf(sqrtf(ssc), 1e-12f);
    float term = 1.0f - dxc * invnx[t] * invnc;

    __shared__ float sterm[4];
    if (lane == 0) sterm[w] = term;
    __syncthreads();
    if (threadIdx.x == 0)
        partials[blockIdx.x] = sterm[0] + sterm[1] + sterm[2] + sterm[3];
}

// ---------------- kernel 5: deterministic loss finalize ----------------
__global__ void finalize_kernel(const float* __restrict__ partials, float* __restrict__ loss) {
    __shared__ float buf[256];
    float s = 0.0f;
    for (int i = threadIdx.x; i < TOKENS / 4; i += 256) s += partials[i];
    buf[threadIdx.x] = s;
    __syncthreads();
    for (int st = 128; st; st >>= 1) {
        if (threadIdx.x < st) buf[threadIdx.x] += buf[threadIdx.x + st];
        __syncthreads();
    }
    if (threadIdx.x == 0) loss[0] = buf[0] * (1.25f / (float)TOKENS);
}

extern "C" void kernel_launch(void* const* d_in, const int* in_sizes, int n_in,
                              void* d_out, int out_size, void* d_ws, size_t ws_size,
                              hipStream_t stream) {
    const float* x  = (const float*)d_in[0];
    const float* cb = (const float*)d_in[1];

    float* out   = (float*)d_out;
    float* ids_f = out;
    float* emb   = out + TOKENS;
    float* loss  = out + TOKENS + (size_t)TOKENS * DIM;

    // workspace layout
    float* ws = (float*)d_ws;
    float* cbn   = ws;                                   // 4096*256 f32 (4MB)
    short* cbh2  = (short*)(cbn + (size_t)KCB * DIM);    // 4096*256 bf16 frag-major (2MB)
    float* xnorm = (float*)(cbh2 + (size_t)KCB * DIM);   // 65536
    float* invnx = xnorm + TOKENS;                       // 65536
    unsigned long long* win = (unsigned long long*)(invnx + TOKENS);   // 65536 u64
    uint32_t* list = (uint32_t*)(win + TOKENS);          // LIST_CAP u32 (8MB)
    uint32_t* cnt  = list + LIST_CAP;                    // 1 u32 (+pad)
    float* partials = (float*)(cnt + 16);                // 16384 f32

    hipMemsetAsync(cnt, 0, 64, stream);
    hipMemsetAsync(win, 0xFF, sizeof(unsigned long long) * TOKENS, stream);

    prep_all<<<KCB / 4 + TOKENS / 4, 256, 0, stream>>>(cb, x, cbn, cbh2, xnorm, invnx);
    mfma_select<<<TOKENS / TB, 512, 0, stream>>>(x, cbh2, xnorm, cbn, invnx, list, cnt, win);
    rescore<<<RBLOCKS, 256, 0, stream>>>(x, cbn, invnx, list, cnt, win);
    epilogue_kernel<<<TOKENS / 4, 256, 0, stream>>>(x, cbn, invnx, win, ids_f, emb, partials);
    finalize_kernel<<<1, 256, 0, stream>>>(partials, loss);
}

// Round 20
// 404.213 us; speedup vs baseline: 2.5627x; 2.5627x over previous
//
#include <hip/hip_runtime.h>
#include <math.h>
#include <stdint.h>

// x: [65536 x 256] f32, codebook: [4096 x 256] f32
// d_out (f32): ids(65536 as float) | emb(65536*256) | loss(1)

#define TOKENS 65536
#define DIM 256
#define KCB 4096

#define TB 256                 // tokens per block; 8 waves = 4 token-quarters x 2 code-halves
#define DELTA_SCALE 0.03125f   // 2^-5 * ||x|| band (sound: >= 4x bf16 dot error bound)
#define LIST_CAP (1u << 21)    // candidate list capacity
#define SCAP 4096              // per-block LDS candidate cap (expected ~1000)
#define RBLOCKS 2048           // rescore grid (XCD-contiguous chunk assignment)

typedef short bf16x8 __attribute__((ext_vector_type(8)));
typedef float f32x4 __attribute__((ext_vector_type(4)));

__device__ inline short f2bf(float f) {  // RNE float->bf16
    uint32_t u = __float_as_uint(f);
    u += 0x7FFF + ((u >> 16) & 1);
    return (short)(u >> 16);
}

// ---------------- kernel 1: fused prep ----------------
__global__ void prep_all(const float* __restrict__ cb, const float* __restrict__ x,
                         float* __restrict__ cbn, short* __restrict__ cbh2,
                         float* __restrict__ xnorm, float* __restrict__ invnx) {
    int bid  = blockIdx.x;
    int w    = threadIdx.x >> 6;
    int lane = threadIdx.x & 63;
    if (bid < KCB / 4) {
        int row = bid * 4 + w;                        // code c
        float4 v = *(const float4*)(cb + (size_t)row * DIM + lane * 4);
        float ss = v.x * v.x + v.y * v.y + v.z * v.z + v.w * v.w;
#pragma unroll
        for (int off = 32; off; off >>= 1) ss += __shfl_xor(ss, off);
        float scale = 1.0f / fmaxf(sqrtf(ss), 1e-12f);
        float4 o = {v.x * scale, v.y * scale, v.z * scale, v.w * scale};
        *(float4*)(cbn + (size_t)row * DIM + lane * 4) = o;
        short4 h = {f2bf(o.x), f2bf(o.y), f2bf(o.z), f2bf(o.w)};
        int g = row >> 4, l15 = row & 15;
        int kst = lane >> 3, q = (lane >> 1) & 3, jhalf = lane & 1;
        size_t dst = ((size_t)((g * 8 + kst) * 64 + q * 16 + l15)) * 8 + jhalf * 4;
        *(short4*)(cbh2 + dst) = h;
    } else {
        int row = (bid - KCB / 4) * 4 + w;            // token t
        float4 v = *(const float4*)(x + (size_t)row * DIM + lane * 4);
        float ss = v.x * v.x + v.y * v.y + v.z * v.z + v.w * v.w;
#pragma unroll
        for (int off = 32; off; off >>= 1) ss += __shfl_xor(ss, off);
        if (lane == 0) {
            float n = fmaxf(sqrtf(ss), 1e-12f);
            xnorm[row] = n;
            invnx[row] = 1.0f / n;
        }
    }
}

// load 8 B-frags for ct index (cti) into buf
#define LOADB(buf, cti)                                                            \
    {                                                                              \
        const short* bp_ = cbh2 + (size_t)(ch * 128 + (cti)) * 4096 + lane * 8;    \
        _Pragma("unroll")                                                          \
        for (int j = 0; j < 8; ++j) buf[j] = *(const bf16x8*)(bp_ + j * 512);      \
    }

// fresh-zero acc, kst-ascending MFMA (bit-identical per-acc chain to R8-R17)
#define COMPUTE(buf)                                                               \
    {                                                                              \
        _Pragma("unroll")                                                          \
        for (int mf = 0; mf < 4; ++mf) acc[mf] = (f32x4){0.f, 0.f, 0.f, 0.f};      \
        _Pragma("unroll")                                                          \
        for (int kst = 0; kst < 8; ++kst)                                          \
            _Pragma("unroll")                                                      \
            for (int mf = 0; mf < 4; ++mf)                                         \
                acc[mf] = __builtin_amdgcn_mfma_f32_16x16x32_bf16(                 \
                    areg[mf][kst], buf[kst], acc[mf], 0, 0, 0);                    \
    }

#define FOLDMAX()                                                                  \
    {                                                                              \
        _Pragma("unroll")                                                          \
        for (int mf = 0; mf < 4; ++mf)                                             \
            _Pragma("unroll")                                                      \
            for (int r = 0; r < 4; ++r)                                            \
                rmax[mf][r] = fmaxf(rmax[mf][r], acc[mf][r]);                      \
    }

#define EXTRACT(cti)                                                               \
    {                                                                              \
        _Pragma("unroll")                                                          \
        for (int mf = 0; mf < 4; ++mf)                                             \
            _Pragma("unroll")                                                      \
            for (int r = 0; r < 4; ++r) {                                          \
                if (acc[mf][r] >= thr[mf][r]) {                                    \
                    uint32_t t = twb + mf * 16 + q * 4 + r;                        \
                    uint32_t c = ch * 2048 + (cti) * 16 + l15;                     \
                    uint32_t e = (t << 12) | c;                                    \
                    uint32_t idx = atomicAdd(&s_cnt, 1u);                          \
                    if (idx < SCAP) s_list[idx] = e;                               \
                    else { uint32_t g2 = atomicAdd(cnt, 1u);                       \
                           if (g2 < LIST_CAP) list[g2] = e; }                      \
                }                                                                  \
            }                                                                      \
    }

// ---------------- kernel 2: two-sweep MFMA select, structurally pipelined B ----------------
// Validated R17 structure: 8 waves (4 token-quarters x 2 code-halves), areg-resident A,
// frag-major coalesced B, double-buffered with sched_barrier(0) pinning LOADB(next)
// before COMPUTE(cur) so the next ct's 8 loads stay in flight under the 32-MFMA block.
__global__ __launch_bounds__(512, 2) void mfma_select(
    const float* __restrict__ x, const short* __restrict__ cbh2,
    const float* __restrict__ xnorm,
    uint32_t* __restrict__ list, uint32_t* __restrict__ cnt) {
    __shared__ uint32_t s_list[SCAP];
    __shared__ uint32_t s_cnt, s_base;
    __shared__ float maxbuf[2][TB];

    const int tid  = threadIdx.x;
    const int lane = tid & 63;
    const int wid  = tid >> 6;
    const int tq   = wid >> 1;          // token quarter (0..3)
    const int ch   = wid & 1;           // code half (0..1)
    const int l15  = lane & 15, q = lane >> 4;
    const int tb   = blockIdx.x * TB;
    const int twb  = tb + tq * 64;      // this wave's 64-token base

    if (tid == 0) s_cnt = 0;

    // ---- load A into registers: 4 mf x 8 kst fragments (tokens twb + mf*16 + l15) ----
    bf16x8 areg[4][8];
#pragma unroll
    for (int mf = 0; mf < 4; ++mf) {
        const float* xr = x + (size_t)(twb + mf * 16 + l15) * DIM + q * 8;
#pragma unroll
        for (int kst = 0; kst < 8; ++kst) {
            float4 f0 = *(const float4*)(xr + kst * 32);
            float4 f1 = *(const float4*)(xr + kst * 32 + 4);
            bf16x8 h;
            h[0] = f2bf(f0.x); h[1] = f2bf(f0.y); h[2] = f2bf(f0.z); h[3] = f2bf(f0.w);
            h[4] = f2bf(f1.x); h[5] = f2bf(f1.y); h[6] = f2bf(f1.z); h[7] = f2bf(f1.w);
            areg[mf][kst] = h;
        }
    }

    float rmax[4][4];
#pragma unroll
    for (int mf = 0; mf < 4; ++mf)
#pragma unroll
        for (int r = 0; r < 4; ++r) rmax[mf][r] = -3.0e38f;

    // ---- phase 0: sweep this wave's 2048 codes (16/ct), exact per-token max ----
    {
        bf16x8 bA[8], bB[8];
        f32x4 acc[4];
        LOADB(bA, 0)
        for (int ct = 0; ct < 128; ct += 2) {
            LOADB(bB, ct + 1)
            __builtin_amdgcn_sched_barrier(0);
            COMPUTE(bA)
            FOLDMAX()
            int ctn = (ct + 2 < 128) ? ct + 2 : 127;  // clamped dummy on last iter
            LOADB(bA, ctn)
            __builtin_amdgcn_sched_barrier(0);
            COMPUTE(bB)
            FOLDMAX()
        }
    }

    // reduce over the 16 col-lanes (same q -> same token rows)
#pragma unroll
    for (int mf = 0; mf < 4; ++mf)
#pragma unroll
        for (int r = 0; r < 4; ++r) {
            float v = rmax[mf][r];
#pragma unroll
            for (int o = 1; o < 16; o <<= 1) v = fmaxf(v, __shfl_xor(v, o));
            rmax[mf][r] = v;
        }
    // combine across the 2 code-half waves sharing each token quarter
    if (l15 == 0) {
#pragma unroll
        for (int mf = 0; mf < 4; ++mf)
#pragma unroll
            for (int r = 0; r < 4; ++r)
                maxbuf[ch][tq * 64 + mf * 16 + q * 4 + r] = rmax[mf][r];
    }
    __syncthreads();
    float thr[4][4];
#pragma unroll
    for (int mf = 0; mf < 4; ++mf)
#pragma unroll
        for (int r = 0; r < 4; ++r) {
            int tl = tq * 64 + mf * 16 + q * 4 + r;
            thr[mf][r] = fmaxf(maxbuf[0][tl], maxbuf[1][tl])
                       - DELTA_SCALE * xnorm[tb + tl];
        }

    // ---- phase 1: identical re-sweep (pipelined), extract exact band into LDS list ----
    {
        bf16x8 bA[8], bB[8];
        f32x4 acc[4];
        LOADB(bA, 0)
        for (int ct = 0; ct < 128; ct += 2) {
            LOADB(bB, ct + 1)
            __builtin_amdgcn_sched_barrier(0);
            COMPUTE(bA)
            EXTRACT(ct)
            int ctn = (ct + 2 < 128) ? ct + 2 : 127;
            LOADB(bA, ctn)
            __builtin_amdgcn_sched_barrier(0);
            COMPUTE(bB)
            EXTRACT(ct + 1)
        }
    }

    // ---- batched copy-out: one global atomic per block (entries block-contiguous) ----
    __syncthreads();
    if (tid == 0) {
        uint32_t m = s_cnt;
        if (m > SCAP) m = SCAP;
        s_base = atomicAdd(cnt, m);
        s_cnt = m;
    }
    __syncthreads();
    for (uint32_t i = tid; i < s_cnt; i += 512) {
        uint32_t idx = s_base + i;
        if (idx < LIST_CAP) list[idx] = s_list[i];
    }
}

// ---------------- kernel 3: fp32 rescore, XCD-contiguous chunks, float4 loads ----------------
// (byte-identical to R16/R17-validated)
__global__ void rescore(const float* __restrict__ x, const float* __restrict__ cbn,
                        const float* __restrict__ invnx,
                        const uint32_t* __restrict__ list, const uint32_t* __restrict__ cnt,
                        unsigned long long* __restrict__ win) {
    uint32_t n = *cnt;
    if (n > LIST_CAP) n = LIST_CAP;
    uint32_t swz = (blockIdx.x & 7) * (RBLOCKS / 8) + (blockIdx.x >> 3);
    uint32_t per = (n + RBLOCKS - 1) / RBLOCKS;
    uint32_t lo  = swz * per;
    uint32_t hi  = lo + per;
    if (hi > n) hi = n;
    for (uint32_t e = lo + threadIdx.x; e < hi; e += blockDim.x) {
        uint32_t v = list[e];
        uint32_t t = v >> 12, c = v & 4095;
        const float4* xp = (const float4*)(x + (size_t)t * DIM);
        const float4* cp = (const float4*)(cbn + (size_t)c * DIM);
        float acc = 0.0f;
#pragma unroll 8
        for (int k = 0; k < DIM / 4; ++k) {
            float4 xv = xp[k];
            float4 cv = cp[k];
            acc = fmaf(xv.x, cv.x, acc);
            acc = fmaf(xv.y, cv.y, acc);
            acc = fmaf(xv.z, cv.z, acc);
            acc = fmaf(xv.w, cv.w, acc);
        }
        float s = acc * invnx[t];
        float dist = 1.0f - s;
        uint32_t u = __float_as_uint(dist);
        u = (u & 0x80000000u) ? ~u : (u | 0x80000000u);  // order-preserving map
        unsigned long long key = ((unsigned long long)u << 32) | c;
        atomicMin(win + t, key);
    }
}

// ---------------- kernel 4: gather + weighted emb + per-block loss partial ----------------
__global__ void epilogue_kernel(const float* __restrict__ x, const float* __restrict__ cbn,
                                const float* __restrict__ invnx,
                                const unsigned long long* __restrict__ win,
                                float* __restrict__ ids_f,
                                float* __restrict__ emb, float* __restrict__ partials) {
    int w    = threadIdx.x >> 6;
    int lane = threadIdx.x & 63;
    int t    = blockIdx.x * 4 + w;
    int id   = (int)(win[t] & 0xFFFFFFFFull);
    if ((unsigned)id > 4095u) id = 0;  // safety: never expected to trigger
    if (lane == 0) ids_f[t] = (float)id;

    float4 c4 = *(const float4*)(cbn + (size_t)id * DIM + lane * 4);
    float4 x4 = *(const float4*)(x + (size_t)t * DIM + lane * 4);
    float dxc = c4.x * x4.x + c4.y * x4.y + c4.z * x4.z + c4.w * x4.w;
    float ssc = c4.x * c4.x + c4.y * c4.y + c4.z * c4.z + c4.w * c4.w;
#pragma unroll
    for (int off = 32; off; off >>= 1) {
        dxc += __shfl_xor(dxc, off);
        ssc += __shfl_xor(ssc, off);
    }
    float cosk = fmaxf(dxc, 1e-6f);
    float4 o = {cosk * c4.x, cosk * c4.y, cosk * c4.z, cosk * c4.w};
    *(float4*)(emb + (size_t)t * DIM + lane * 4) = o;

    float invnc = 1.0f / fmaxf(sqrtf(ssc), 1e-12f);
    float term = 1.0f - dxc * invnx[t] * invnc;

    __shared__ float sterm[4];
    if (lane == 0) sterm[w] = term;
    __syncthreads();
    if (threadIdx.x == 0)
        partials[blockIdx.x] = sterm[0] + sterm[1] + sterm[2] + sterm[3];
}

// ---------------- kernel 5: deterministic loss finalize ----------------
__global__ void finalize_kernel(const float* __restrict__ partials, float* __restrict__ loss) {
    __shared__ float buf[256];
    float s = 0.0f;
    for (int i = threadIdx.x; i < TOKENS / 4; i += 256) s += partials[i];
    buf[threadIdx.x] = s;
    __syncthreads();
    for (int st = 128; st; st >>= 1) {
        if (threadIdx.x < st) buf[threadIdx.x] += buf[threadIdx.x + st];
        __syncthreads();
    }
    if (threadIdx.x == 0) loss[0] = buf[0] * (1.25f / (float)TOKENS);
}

extern "C" void kernel_launch(void* const* d_in, const int* in_sizes, int n_in,
                              void* d_out, int out_size, void* d_ws, size_t ws_size,
                              hipStream_t stream) {
    const float* x  = (const float*)d_in[0];
    const float* cb = (const float*)d_in[1];

    float* out   = (float*)d_out;
    float* ids_f = out;
    float* emb   = out + TOKENS;
    float* loss  = out + TOKENS + (size_t)TOKENS * DIM;

    // workspace layout
    float* ws = (float*)d_ws;
    float* cbn   = ws;                                   // 4096*256 f32 (4MB)
    short* cbh2  = (short*)(cbn + (size_t)KCB * DIM);    // 4096*256 bf16 frag-major (2MB)
    float* xnorm = (float*)(cbh2 + (size_t)KCB * DIM);   // 65536
    float* invnx = xnorm + TOKENS;                       // 65536
    unsigned long long* win = (unsigned long long*)(invnx + TOKENS);   // 65536 u64
    uint32_t* list = (uint32_t*)(win + TOKENS);          // LIST_CAP u32 (8MB)
    uint32_t* cnt  = list + LIST_CAP;                    // 1 u32 (+pad)
    float* partials = (float*)(cnt + 16);                // 16384 f32

    hipMemsetAsync(cnt, 0, 64, stream);
    hipMemsetAsync(win, 0xFF, sizeof(unsigned long long) * TOKENS, stream);

    prep_all<<<KCB / 4 + TOKENS / 4, 256, 0, stream>>>(cb, x, cbn, cbh2, xnorm, invnx);
    mfma_select<<<TOKENS / TB, 512, 0, stream>>>(x, cbh2, xnorm, list, cnt);
    rescore<<<RBLOCKS, 256, 0, stream>>>(x, cbn, invnx, list, cnt, win);
    epilogue_kernel<<<TOKENS / 4, 256, 0, stream>>>(x, cbn, invnx, win, ids_f, emb, partials);
    finalize_kernel<<<1, 256, 0, stream>>>(partials, loss);
}